// Round 4
// baseline (283.581 us; speedup 1.0000x reference)
//
#include <hip/hip_runtime.h>
#include <math.h>

// OscillatoryAttention: B=2,S=2048,D=1024,H=16,dk=64. FP32 in/out, bf16 MFMA inside.
// R4: (a) GEMMs use global_load_lds width-16 (m97 recipe), out-GEMM 64-row tiles;
// (b) attention computes S^T so P^T lands in C-layout == 16x16x16 B-frag layout:
//     exp2 -> pack -> PV MFMA with NO LDS round-trip; V kept natural [d][j];
//     row-sums via immediate ones A-frag; 128-thr blocks, grid 1024.

#define S_LEN 2048
#define NHEADS 16

typedef __attribute__((ext_vector_type(8))) short short8;
typedef __attribute__((ext_vector_type(4))) short short4v;
typedef __attribute__((ext_vector_type(4))) float floatx4;

__device__ inline unsigned short f2bf(float f) {
    union { float f; unsigned int i; } v; v.f = f;
    unsigned int u = v.i;
    return (unsigned short)((u + 0x7fffu + ((u >> 16) & 1u)) >> 16);
}
// pack two f32 -> packed bf16 u32 (truncation), low16 = lo
__device__ inline unsigned int pack2_bf16(float hi, float lo) {
    union { float f; unsigned int u; } a, b; a.f = hi; b.f = lo;
    return __builtin_amdgcn_perm(a.u, b.u, 0x07060302u);
}
// async global->LDS 16B: LDS dest must be wave-uniform base + lane*16
__device__ inline void async_copy16(const unsigned short* src, unsigned short* dst_lds) {
    __builtin_amdgcn_global_load_lds(
        (const __attribute__((address_space(1))) unsigned int*)(src),
        (__attribute__((address_space(3))) unsigned int*)(dst_lds),
        16, 0, 0);
}

// ---------------- weight transpose+cvt: WT[n][k] = bf16(W[k][n]) ----------------
__global__ __launch_bounds__(256) void transpose4(
    const float* __restrict__ w0, const float* __restrict__ w1,
    const float* __restrict__ w2, const float* __restrict__ w3,
    unsigned short* __restrict__ d0, unsigned short* __restrict__ d1,
    unsigned short* __restrict__ d2, unsigned short* __restrict__ d3) {
    __shared__ __align__(16) unsigned short tile[64][72];
    int bid = blockIdx.x;
    int mat = bid >> 8;
    int tl  = bid & 255;
    int tr = tl >> 4, tc = tl & 15;
    const float* src    = (mat == 0) ? w0 : (mat == 1) ? w1 : (mat == 2) ? w2 : w3;
    unsigned short* dst = (mat == 0) ? d0 : (mat == 1) ? d1 : (mat == 2) ? d2 : d3;
    int t = threadIdx.x;
    int col = t & 63, rbase = (t >> 6) * 16;
#pragma unroll
    for (int i = 0; i < 16; i++) {
        int row = rbase + i;
        tile[row][col] = f2bf(src[(size_t)(tr * 64 + row) * 1024 + tc * 64 + col]);
    }
    __syncthreads();
#pragma unroll
    for (int i = 0; i < 16; i++) {
        int row = rbase + i;
        dst[(size_t)(tc * 64 + row) * 1024 + tr * 64 + col] = tile[col][row];
    }
}

// ---------------- phase + x->bf16: phi = x@Wp + bp; cos/sin at [b][h][s] --------
__global__ __launch_bounds__(256) void phase_cvt(
    const float* __restrict__ x, const float* __restrict__ Wp,
    const float* __restrict__ bp,
    float* __restrict__ cosP, float* __restrict__ sinP,
    unsigned short* __restrict__ xb) {
    __shared__ float red[256];
    int bid = blockIdx.x;
    int b = bid >> 11, s = bid & 2047;
    int t = threadIdx.x;
    int h = t & 15, c = t >> 4;
    const float* xr = x + (size_t)bid * 1024;
    // bf16 conversion of this row (coalesced 8B stores)
    {
        float4 xv = *reinterpret_cast<const float4*>(&xr[t * 4]);
        uint2 o;
        o.x = (unsigned int)f2bf(xv.x) | ((unsigned int)f2bf(xv.y) << 16);
        o.y = (unsigned int)f2bf(xv.z) | ((unsigned int)f2bf(xv.w) << 16);
        *reinterpret_cast<uint2*>(&xb[(size_t)bid * 1024 + t * 4]) = o;
    }
    float acc = 0.f;
#pragma unroll 8
    for (int kk = 0; kk < 64; kk++) {
        int k = c * 64 + kk;
        acc += xr[k] * Wp[k * 16 + h];
    }
    red[t] = acc;
    __syncthreads();
    if (t < 16) {
        float sum = 0.f;
#pragma unroll
        for (int c2 = 0; c2 < 16; c2++) sum += red[c2 * 16 + t];
        sum += bp[t];
        float sv, cv;
        __sincosf(sum, &sv, &cv);
        size_t o = ((size_t)b * NHEADS + t) * S_LEN + s;
        cosP[o] = cv; sinP[o] = sv;
    }
}

// ---------------- GEMM: C[4096][N] = A[4096][1024] @ BT[N][1024]^T (bf16) -------
// m97 recipe: global_load_lds 16B into unpadded [rows][32] LDS tiles.
// mode 0: row-major fp32 out (+bias) -> of
// mode 1: N=3072 QKV: Q->(B,H,S,dk) scaled 0.125*log2e; K->(B,H,S,dk);
//         V->TRANSPOSED (B,H,dk,S) via packed dwordx2 stores.
template <int MT>
__global__ __launch_bounds__(256) void gemm_bt(
    const unsigned short* __restrict__ A, const unsigned short* __restrict__ BT,
    int N, int mode,
    const float* __restrict__ b0, const float* __restrict__ b1,
    const float* __restrict__ b2,
    unsigned short* __restrict__ o0, unsigned short* __restrict__ o1,
    unsigned short* __restrict__ o2, float* __restrict__ of) {
    __shared__ __align__(16) unsigned short As[MT * 32];
    __shared__ __align__(16) unsigned short Bs[128 * 32];
    const int K = 1024;
    const int MI = MT / 32;
    int t = threadIdx.x;
    int mBase = blockIdx.x * MT;
    int nBase = blockIdx.y * 128;
    int w = t >> 6, lane = t & 63, l15 = lane & 15, quad = lane >> 4;
    int wm = (w & 1) * (MT / 2), wn = (w >> 1) * 64;
    floatx4 acc[MI][4];
#pragma unroll
    for (int i = 0; i < MI; i++)
#pragma unroll
        for (int j = 0; j < 4; j++) acc[i][j] = (floatx4){0.f, 0.f, 0.f, 0.f};

    int arow = t >> 2, aseg = (t & 3) * 8;   // lds byte off = t*16 (+ pass*4096)
    for (int k0 = 0; k0 < K; k0 += 32) {
        __syncthreads();
#pragma unroll
        for (int i = 0; i < MT / 64; i++)
            async_copy16(&A[(size_t)(mBase + i * 64 + arow) * K + k0 + aseg],
                         &As[(i * 64 + arow) * 32 + aseg]);
#pragma unroll
        for (int i = 0; i < 2; i++)
            async_copy16(&BT[(size_t)(nBase + i * 64 + arow) * K + k0 + aseg],
                         &Bs[(i * 64 + arow) * 32 + aseg]);
        __syncthreads();
        short8 af[MI], bfr[4];
#pragma unroll
        for (int mi = 0; mi < MI; mi++)
            af[mi] = *reinterpret_cast<const short8*>(&As[(wm + mi * 16 + l15) * 32 + quad * 8]);
#pragma unroll
        for (int ni = 0; ni < 4; ni++)
            bfr[ni] = *reinterpret_cast<const short8*>(&Bs[(wn + ni * 16 + l15) * 32 + quad * 8]);
#pragma unroll
        for (int mi = 0; mi < MI; mi++)
#pragma unroll
            for (int ni = 0; ni < 4; ni++)
                acc[mi][ni] = __builtin_amdgcn_mfma_f32_16x16x32_bf16(af[mi], bfr[ni], acc[mi][ni], 0, 0, 0);
    }

#pragma unroll
    for (int mi = 0; mi < MI; mi++) {
        int rowB = mBase + wm + mi * 16 + quad * 4;
#pragma unroll
        for (int ni = 0; ni < 4; ni++) {
            int col = nBase + wn + ni * 16 + l15;
            if (mode == 0) {
                float bias = b0[col];
#pragma unroll
                for (int r = 0; r < 4; r++) {
                    of[(size_t)(rowB + r) * N + col] = acc[mi][ni][r] + bias;
                }
            } else {
                int mat = col >> 10, nn = col & 1023;
                int h = nn >> 6, d = nn & 63;
                int b = rowB >> 11, sidx = rowB & 2047;
                if (mat == 2) {
                    float bv = b2[nn];
                    unsigned int lo = (unsigned int)f2bf(acc[mi][ni][0] + bv) |
                                      ((unsigned int)f2bf(acc[mi][ni][1] + bv) << 16);
                    unsigned int hi = (unsigned int)f2bf(acc[mi][ni][2] + bv) |
                                      ((unsigned int)f2bf(acc[mi][ni][3] + bv) << 16);
                    *reinterpret_cast<uint2*>(
                        &o2[((size_t)((b * NHEADS + h) * 64 + d)) * S_LEN + sidx]) =
                        make_uint2(lo, hi);
                } else {
                    const float* bias  = (mat == 0) ? b0 : b1;
                    unsigned short* op = (mat == 0) ? o0 : o1;
                    float bv = bias[nn];
                    float scl = (mat == 0) ? 0.18033688f : 1.0f;  // dk^-0.5 * log2e
#pragma unroll
                    for (int r = 0; r < 4; r++) {
                        float cv = (acc[mi][ni][r] + bv) * scl;
                        op[(((size_t)b * NHEADS + h) * S_LEN + (sidx + r)) * 64 + d] = f2bf(cv);
                    }
                }
            }
        }
    }
}

// ---------------- flash attention, oscillatory coherence ------------------------
// grid = B*H*(S/64) = 1024 blocks, 128 thr (2 waves x 32 Q-cols each).
// S^T = mfma(A=K_j, B=Q_i); P^T = exp2(S^T + ci*cj + si*sj) in C-layout ==
// B-frag layout of 16x16x16 -> PV directly from registers. l via ones A-frag.
__global__ __launch_bounds__(128) void attn_kernel(
    const unsigned short* __restrict__ Qg, const unsigned short* __restrict__ Kg,
    const unsigned short* __restrict__ VTg,
    const float* __restrict__ cosP, const float* __restrict__ sinP,
    const float* __restrict__ alpha, unsigned short* __restrict__ ctx) {
    __shared__ __align__(16) unsigned short Ks[64][72];   // rows j, cols d
    __shared__ __align__(16) unsigned short Vt[64][72];   // rows d, cols j
    __shared__ __align__(16) float cjs[64];
    __shared__ __align__(16) float sjs[64];

    int bid = blockIdx.x;
    int bh = bid >> 5, qt = bid & 31;
    int t = threadIdx.x, w = t >> 6, lane = t & 63, l15 = lane & 15, quad = lane >> 4;
    int i0w = qt * 64 + w * 32;                 // this wave's 32 query cols
    size_t base = (size_t)bh * (S_LEN * 64);    // same for (B,H,S,dk) and (B,H,dk,S)
    size_t phBase = (size_t)bh * S_LEN;
    const float L2E = 1.44269504f;

    // Q B-frags (pre-scaled by 0.125*L2E in GEMM): B[k=d][n=i]
    short8 qf[2][2];
#pragma unroll
    for (int it = 0; it < 2; it++)
#pragma unroll
        for (int c = 0; c < 2; c++)
            qf[it][c] = *reinterpret_cast<const short8*>(
                &Qg[base + (size_t)(i0w + it * 16 + l15) * 64 + c * 32 + quad * 8]);

    float alph = alpha[bh & 15] * L2E;
    float a_ci[2], a_si[2];
#pragma unroll
    for (int it = 0; it < 2; it++) {
        a_ci[it] = alph * cosP[phBase + i0w + it * 16 + l15];
        a_si[it] = alph * sinP[phBase + i0w + it * 16 + l15];
    }

    floatx4 oacc[4][2];   // [dt][it]  O^T(d,i)
    floatx4 lacc[2];      // row-sums l(i)
#pragma unroll
    for (int dt = 0; dt < 4; dt++)
#pragma unroll
        for (int it = 0; it < 2; it++) oacc[dt][it] = (floatx4){0.f, 0.f, 0.f, 0.f};
    lacc[0] = (floatx4){0.f, 0.f, 0.f, 0.f};
    lacc[1] = (floatx4){0.f, 0.f, 0.f, 0.f};

    const short4v ones4 = {(short)0x3F80, (short)0x3F80, (short)0x3F80, (short)0x3F80};
    int srow = t >> 3, sseg = (t & 7) * 8;

    for (int kt = 0; kt < 32; kt++) {
        __syncthreads();
#pragma unroll
        for (int p = 0; p < 4; p++) {
            int row = p * 16 + srow;
            *reinterpret_cast<short8*>(&Ks[row][sseg]) = *reinterpret_cast<const short8*>(
                &Kg[base + (size_t)(kt * 64 + row) * 64 + sseg]);
            *reinterpret_cast<short8*>(&Vt[row][sseg]) = *reinterpret_cast<const short8*>(
                &VTg[base + (size_t)row * S_LEN + kt * 64 + sseg]);
        }
        if (t < 64) cjs[t] = cosP[phBase + kt * 64 + t];
        else        sjs[t - 64] = sinP[phBase + kt * 64 + (t - 64)];
        __syncthreads();

        // S^T(j,i): A = K rows j from LDS, B = Q from registers
        floatx4 st[4][2];
#pragma unroll
        for (int jt = 0; jt < 4; jt++) {
            short8 ka0 = *reinterpret_cast<const short8*>(&Ks[jt * 16 + l15][quad * 8]);
            short8 ka1 = *reinterpret_cast<const short8*>(&Ks[jt * 16 + l15][32 + quad * 8]);
#pragma unroll
            for (int it = 0; it < 2; it++) {
                floatx4 s = (floatx4){0.f, 0.f, 0.f, 0.f};
                s = __builtin_amdgcn_mfma_f32_16x16x32_bf16(ka0, qf[it][0], s, 0, 0, 0);
                s = __builtin_amdgcn_mfma_f32_16x16x32_bf16(ka1, qf[it][1], s, 0, 0, 0);
                st[jt][it] = s;
            }
        }

        // P^T = exp2(S^T + coherence); pack to B-frag regs (k = quad*4 + r)
        short4v pb[4][2];
#pragma unroll
        for (int jt = 0; jt < 4; jt++) {
            floatx4 cj4 = *reinterpret_cast<const floatx4*>(&cjs[jt * 16 + quad * 4]);
            floatx4 sj4 = *reinterpret_cast<const floatx4*>(&sjs[jt * 16 + quad * 4]);
#pragma unroll
            for (int it = 0; it < 2; it++) {
                float p0 = __builtin_amdgcn_exp2f(st[jt][it][0] + a_ci[it] * cj4[0] + a_si[it] * sj4[0]);
                float p1 = __builtin_amdgcn_exp2f(st[jt][it][1] + a_ci[it] * cj4[1] + a_si[it] * sj4[1]);
                float p2 = __builtin_amdgcn_exp2f(st[jt][it][2] + a_ci[it] * cj4[2] + a_si[it] * sj4[2]);
                float p3 = __builtin_amdgcn_exp2f(st[jt][it][3] + a_ci[it] * cj4[3] + a_si[it] * sj4[3]);
                union { unsigned int u[2]; short4v s; } pk;
                pk.u[0] = pack2_bf16(p1, p0);
                pk.u[1] = pack2_bf16(p3, p2);
                pb[jt][it] = pk.s;
            }
        }

        // O^T += V^T(d,j) @ P^T(j,i); l += ones @ P^T
#pragma unroll
        for (int jt = 0; jt < 4; jt++) {
#pragma unroll
            for (int dt = 0; dt < 4; dt++) {
                short4v va = *reinterpret_cast<const short4v*>(&Vt[dt * 16 + l15][jt * 16 + quad * 4]);
#pragma unroll
                for (int it = 0; it < 2; it++)
                    oacc[dt][it] = __builtin_amdgcn_mfma_f32_16x16x16bf16_1k(va, pb[jt][it], oacc[dt][it], 0, 0, 0);
            }
#pragma unroll
            for (int it = 0; it < 2; it++)
                lacc[it] = __builtin_amdgcn_mfma_f32_16x16x16bf16_1k(ones4, pb[jt][it], lacc[it], 0, 0, 0);
        }
    }

    // epilogue: every reg of lacc[it] equals l(i) -> no shuffles needed
    int b = bh >> 4, h = bh & 15;
#pragma unroll
    for (int it = 0; it < 2; it++) {
        float inv = 1.0f / lacc[it][0];
        size_t rowOff = ((size_t)(b * S_LEN + i0w + it * 16 + l15)) * 1024 + h * 64;
#pragma unroll
        for (int dt = 0; dt < 4; dt++) {
            float v0 = oacc[dt][it][0] * inv, v1 = oacc[dt][it][1] * inv;
            float v2 = oacc[dt][it][2] * inv, v3 = oacc[dt][it][3] * inv;
            uint2 o;
            o.x = (unsigned int)f2bf(v0) | ((unsigned int)f2bf(v1) << 16);
            o.y = (unsigned int)f2bf(v2) | ((unsigned int)f2bf(v3) << 16);
            *reinterpret_cast<uint2*>(&ctx[rowOff + dt * 16 + quad * 4]) = o;
        }
    }
}

extern "C" void kernel_launch(void* const* d_in, const int* in_sizes, int n_in,
                              void* d_out, int out_size, void* d_ws, size_t ws_size,
                              hipStream_t stream) {
    const float* x     = (const float*)d_in[0];
    const float* Wq    = (const float*)d_in[1];
    const float* bq    = (const float*)d_in[2];
    const float* Wk    = (const float*)d_in[3];
    const float* bk    = (const float*)d_in[4];
    const float* Wv    = (const float*)d_in[5];
    const float* bv    = (const float*)d_in[6];
    const float* Wo    = (const float*)d_in[7];
    const float* bo    = (const float*)d_in[8];
    const float* Wp    = (const float*)d_in[9];
    const float* bp    = (const float*)d_in[10];
    const float* alpha = (const float*)d_in[11];
    float* out = (float*)d_out;

    const size_t MB = 1048576;
    char* ws = (char*)d_ws;
    unsigned short* WT   = (unsigned short*)(ws);             // 3072x1024 bf16
    unsigned short* WoT  = (unsigned short*)(ws + 6 * MB);    // 1024x1024 bf16
    unsigned short* xb   = (unsigned short*)(ws + 8 * MB);    // (B,S,D) bf16
    unsigned short* ctx  = (unsigned short*)(ws + 8 * MB);    // aliases xb (dead after QKV)
    unsigned short* Qw   = (unsigned short*)(ws + 16 * MB);   // (B,H,S,dk), pre-scaled
    unsigned short* Kw   = (unsigned short*)(ws + 24 * MB);   // (B,H,S,dk)
    unsigned short* VTg  = (unsigned short*)(ws + 32 * MB);   // (B,H,dk,S) transposed
    float* cosP          = (float*)(ws + 40 * MB);            // (B,H,S) fp32
    float* sinP          = (float*)(ws + 40 * MB + 262144);

    transpose4<<<dim3(1024), dim3(256), 0, stream>>>(
        Wq, Wk, Wv, Wo, WT, WT + 1048576, WT + 2097152, WoT);
    phase_cvt<<<dim3(4096), dim3(256), 0, stream>>>(
        x, Wp, bp, cosP, sinP, xb);
    gemm_bt<128><<<dim3(32, 24), dim3(256), 0, stream>>>(
        xb, WT, 3072, 1, bq, bk, bv, Qw, Kw, VTg, (float*)nullptr);
    attn_kernel<<<dim3(1024), dim3(128), 0, stream>>>(
        Qw, Kw, VTg, cosP, sinP, alpha, ctx);
    gemm_bt<64><<<dim3(64, 8), dim3(256), 0, stream>>>(
        ctx, WoT, 1024, 0, bo, bo, bo,
        (unsigned short*)nullptr, (unsigned short*)nullptr,
        (unsigned short*)nullptr, out);
}

// Round 5
// 242.526 us; speedup vs baseline: 1.1693x; 1.1693x over previous
//
#include <hip/hip_runtime.h>
#include <math.h>

// OscillatoryAttention: B=2,S=2048,D=1024,H=16,dk=64. FP32 in/out, bf16 MFMA inside.
// R5: attention = R3 skeleton (4 waves x 32 Q-rows, 16x16x32 everywhere) +
//  (1) global_load_lds double-buffered staging, 1 barrier/iter, prefetch of kt+1;
//  (2) swizzled unpadded [64][64] LDS tiles: row r rotated by 16*(r&7) bytes ->
//      b128 frag reads are <=2-way bank aliased AND staging keeps the
//      base+16*lane contiguous mapping global_load_lds requires;
//  (3) V^T pi-interleave pre-applied in-place by vtrans (out of the hot loop).

#define S_LEN 2048
#define NHEADS 16

typedef __attribute__((ext_vector_type(8))) short short8;
typedef __attribute__((ext_vector_type(4))) float floatx4;
typedef __attribute__((ext_vector_type(4))) unsigned int uintx4;

__device__ inline unsigned short f2bf(float f) {
    union { float f; unsigned int i; } v; v.f = f;
    unsigned int u = v.i;
    return (unsigned short)((u + 0x7fffu + ((u >> 16) & 1u)) >> 16);
}
// pack two f32 -> packed bf16 u32 (truncation), low short = lo
__device__ inline unsigned int pack2_bf16(float hi, float lo) {
    union { float f; unsigned int u; } a, b; a.f = hi; b.f = lo;
    return __builtin_amdgcn_perm(a.u, b.u, 0x07060302u);
}
__device__ inline void async_copy16(const unsigned short* src, unsigned short* dst_lds) {
    __builtin_amdgcn_global_load_lds(
        (const __attribute__((address_space(1))) unsigned int*)(src),
        (__attribute__((address_space(3))) unsigned int*)(dst_lds), 16, 0, 0);
}
__device__ inline void async_copy4(const float* src, float* dst_lds) {
    __builtin_amdgcn_global_load_lds(
        (const __attribute__((address_space(1))) unsigned int*)(src),
        (__attribute__((address_space(3))) unsigned int*)(dst_lds), 4, 0, 0);
}

// ---------------- weight transpose+cvt: WT[n][k] = bf16(W[k][n]) ----------------
__global__ __launch_bounds__(256) void transpose4(
    const float* __restrict__ w0, const float* __restrict__ w1,
    const float* __restrict__ w2, const float* __restrict__ w3,
    unsigned short* __restrict__ d0, unsigned short* __restrict__ d1,
    unsigned short* __restrict__ d2, unsigned short* __restrict__ d3) {
    __shared__ __align__(16) unsigned short tile[64][72];
    int bid = blockIdx.x;
    int mat = bid >> 8;
    int tl  = bid & 255;
    int tr = tl >> 4, tc = tl & 15;
    const float* src    = (mat == 0) ? w0 : (mat == 1) ? w1 : (mat == 2) ? w2 : w3;
    unsigned short* dst = (mat == 0) ? d0 : (mat == 1) ? d1 : (mat == 2) ? d2 : d3;
    int t = threadIdx.x;
    int col = t & 63, rbase = (t >> 6) * 16;
#pragma unroll
    for (int i = 0; i < 16; i++) {
        int row = rbase + i;
        tile[row][col] = f2bf(src[(size_t)(tr * 64 + row) * 1024 + tc * 64 + col]);
    }
    __syncthreads();
#pragma unroll
    for (int i = 0; i < 16; i++) {
        int row = rbase + i;
        dst[(size_t)(tc * 64 + row) * 1024 + tr * 64 + col] = tile[col][row];
    }
}

// ---------------- phase + x->bf16 -----------------------------------------------
__global__ __launch_bounds__(256) void phase_cvt(
    const float* __restrict__ x, const float* __restrict__ Wp,
    const float* __restrict__ bp,
    float* __restrict__ cosP, float* __restrict__ sinP,
    unsigned short* __restrict__ xb) {
    __shared__ float red[256];
    int bid = blockIdx.x;
    int b = bid >> 11, s = bid & 2047;
    int t = threadIdx.x;
    int h = t & 15, c = t >> 4;
    const float* xr = x + (size_t)bid * 1024;
    {
        float4 xv = *reinterpret_cast<const float4*>(&xr[t * 4]);
        uint2 o;
        o.x = (unsigned int)f2bf(xv.x) | ((unsigned int)f2bf(xv.y) << 16);
        o.y = (unsigned int)f2bf(xv.z) | ((unsigned int)f2bf(xv.w) << 16);
        *reinterpret_cast<uint2*>(&xb[(size_t)bid * 1024 + t * 4]) = o;
    }
    float acc = 0.f;
#pragma unroll 8
    for (int kk = 0; kk < 64; kk++) {
        int k = c * 64 + kk;
        acc += xr[k] * Wp[k * 16 + h];
    }
    red[t] = acc;
    __syncthreads();
    if (t < 16) {
        float sum = 0.f;
#pragma unroll
        for (int c2 = 0; c2 < 16; c2++) sum += red[c2 * 16 + t];
        sum += bp[t];
        float sv, cv;
        __sincosf(sum, &sv, &cv);
        size_t o = ((size_t)b * NHEADS + t) * S_LEN + s;
        cosP[o] = cv; sinP[o] = sv;
    }
}

// ---------------- GEMM (m97 recipe) ---------------------------------------------
// mode 0: row-major fp32 out (+bias) -> of
// mode 1: N=3072 QKV: Q scaled 0.125*log2e -> (B,H,S,dk); K -> (B,H,S,dk);
//         V -> (B,H,dk,S) transposed (natural token order; vtrans interleaves after)
template <int MT>
__global__ __launch_bounds__(256) void gemm_bt(
    const unsigned short* __restrict__ A, const unsigned short* __restrict__ BT,
    int N, int mode,
    const float* __restrict__ b0, const float* __restrict__ b1,
    const float* __restrict__ b2,
    unsigned short* __restrict__ o0, unsigned short* __restrict__ o1,
    unsigned short* __restrict__ o2, float* __restrict__ of) {
    __shared__ __align__(16) unsigned short As[MT * 32];
    __shared__ __align__(16) unsigned short Bs[128 * 32];
    const int K = 1024;
    const int MI = MT / 32;
    int t = threadIdx.x;
    int mBase = blockIdx.x * MT;
    int nBase = blockIdx.y * 128;
    int w = t >> 6, lane = t & 63, l15 = lane & 15, quad = lane >> 4;
    int wm = (w & 1) * (MT / 2), wn = (w >> 1) * 64;
    floatx4 acc[MI][4];
#pragma unroll
    for (int i = 0; i < MI; i++)
#pragma unroll
        for (int j = 0; j < 4; j++) acc[i][j] = (floatx4){0.f, 0.f, 0.f, 0.f};

    int arow = t >> 2, aseg = (t & 3) * 8;
    for (int k0 = 0; k0 < K; k0 += 32) {
        __syncthreads();
#pragma unroll
        for (int i = 0; i < MT / 64; i++)
            async_copy16(&A[(size_t)(mBase + i * 64 + arow) * K + k0 + aseg],
                         &As[(i * 64 + arow) * 32 + aseg]);
#pragma unroll
        for (int i = 0; i < 2; i++)
            async_copy16(&BT[(size_t)(nBase + i * 64 + arow) * K + k0 + aseg],
                         &Bs[(i * 64 + arow) * 32 + aseg]);
        __syncthreads();
        short8 af[MI], bfr[4];
#pragma unroll
        for (int mi = 0; mi < MI; mi++)
            af[mi] = *reinterpret_cast<const short8*>(&As[(wm + mi * 16 + l15) * 32 + quad * 8]);
#pragma unroll
        for (int ni = 0; ni < 4; ni++)
            bfr[ni] = *reinterpret_cast<const short8*>(&Bs[(wn + ni * 16 + l15) * 32 + quad * 8]);
#pragma unroll
        for (int mi = 0; mi < MI; mi++)
#pragma unroll
            for (int ni = 0; ni < 4; ni++)
                acc[mi][ni] = __builtin_amdgcn_mfma_f32_16x16x32_bf16(af[mi], bfr[ni], acc[mi][ni], 0, 0, 0);
    }

#pragma unroll
    for (int mi = 0; mi < MI; mi++) {
        int rowB = mBase + wm + mi * 16 + quad * 4;
#pragma unroll
        for (int ni = 0; ni < 4; ni++) {
            int col = nBase + wn + ni * 16 + l15;
            if (mode == 0) {
                float bias = b0[col];
#pragma unroll
                for (int r = 0; r < 4; r++) {
                    of[(size_t)(rowB + r) * N + col] = acc[mi][ni][r] + bias;
                }
            } else {
                int mat = col >> 10, nn = col & 1023;
                int h = nn >> 6, d = nn & 63;
                int b = rowB >> 11, sidx = rowB & 2047;
                if (mat == 2) {
                    float bv = b2[nn];
                    unsigned int lo = (unsigned int)f2bf(acc[mi][ni][0] + bv) |
                                      ((unsigned int)f2bf(acc[mi][ni][1] + bv) << 16);
                    unsigned int hi = (unsigned int)f2bf(acc[mi][ni][2] + bv) |
                                      ((unsigned int)f2bf(acc[mi][ni][3] + bv) << 16);
                    *reinterpret_cast<uint2*>(
                        &o2[((size_t)((b * NHEADS + h) * 64 + d)) * S_LEN + sidx]) =
                        make_uint2(lo, hi);
                } else {
                    const float* bias  = (mat == 0) ? b0 : b1;
                    unsigned short* op = (mat == 0) ? o0 : o1;
                    float bv = bias[nn];
                    float scl = (mat == 0) ? 0.18033688f : 1.0f;  // dk^-0.5 * log2e
#pragma unroll
                    for (int r = 0; r < 4; r++) {
                        float cv = (acc[mi][ni][r] + bv) * scl;
                        op[(((size_t)b * NHEADS + h) * S_LEN + (sidx + r)) * 64 + d] = f2bf(cv);
                    }
                }
            }
        }
    }
}

// ---------------- vtrans: in-place pi-interleave of V^T 64-token tiles ----------
// pi(u) = (u>>5)*32 + (u&1)*16 + ((u>>1)&15); out short u <- in short pi(u),
// applied independently within every 128-byte tile. One 4 kB chunk per block.
__global__ __launch_bounds__(256) void vtrans(unsigned int* __restrict__ v) {
    __shared__ unsigned int ld[1024];
    size_t base = (size_t)blockIdx.x * 1024;
    int t = threadIdx.x;
    *reinterpret_cast<uintx4*>(&ld[t * 4]) =
        *reinterpret_cast<const uintx4*>(&v[base + t * 4]);
    __syncthreads();
    int tile = t >> 3, m = t & 7;
    int b = ((m >> 2) << 4) + ((m & 3) << 1);
    const unsigned int* tb = &ld[tile * 32];
    unsigned int a0 = tb[b], a1 = tb[b + 1], h0 = tb[b + 8], h1 = tb[b + 9];
    uintx4 o;
    o[0] = __builtin_amdgcn_perm(h0, a0, 0x05040100u);
    o[1] = __builtin_amdgcn_perm(h0, a0, 0x07060302u);
    o[2] = __builtin_amdgcn_perm(h1, a1, 0x05040100u);
    o[3] = __builtin_amdgcn_perm(h1, a1, 0x07060302u);
    *reinterpret_cast<uintx4*>(&v[base + t * 4]) = o;
}

// ---------------- flash attention, oscillatory coherence ------------------------
// grid = B*H*(S/128) = 512 blocks, 256 thr (4 waves x 32 Q-rows).
// Double-buffered async staging, swizzled LDS, 1 barrier/iter.
__global__ __launch_bounds__(256) void attn_kernel(
    const unsigned short* __restrict__ Qg, const unsigned short* __restrict__ Kg,
    const unsigned short* __restrict__ VTg,
    const float* __restrict__ cosP, const float* __restrict__ sinP,
    const float* __restrict__ alpha, unsigned short* __restrict__ ctx) {
    __shared__ __align__(16) unsigned short KsB[2][64 * 64];
    __shared__ __align__(16) unsigned short VtB[2][64 * 64];
    __shared__ __align__(16) float csB[2][128];          // cos 0..63, sin 64..127
    __shared__ __align__(16) unsigned short Plb[4][32 * 72];

    int bid = blockIdx.x;
    int bh = bid >> 4, qt = bid & 15;
    int t = threadIdx.x, w = t >> 6, lane = t & 63, l15 = lane & 15, quad = lane >> 4;
    int m0 = qt * 128 + w * 32;
    size_t base = (size_t)bh * (S_LEN * 64);
    size_t phBase = (size_t)bh * S_LEN;
    const float L2E = 1.44269504f;

    // staging geometry: thread t owns LDS bytes 16t (+4096); row j = t>>3, group g = t&7.
    int sj = t >> 3, sg = t & 7;
    int srot = ((sg - (sj & 7)) & 7) * 8;   // shorts: un-rotated global column

    // prologue: Q frags (A-layout), ci/si, stage tile 0 into buf 0
    short8 qf[2][2];
#pragma unroll
    for (int mi = 0; mi < 2; mi++)
#pragma unroll
        for (int c = 0; c < 2; c++)
            qf[mi][c] = *reinterpret_cast<const short8*>(
                &Qg[base + (size_t)(m0 + mi * 16 + l15) * 64 + c * 32 + quad * 8]);

    float alph = alpha[bh & 15] * L2E;
    float ci[2][4], si[2][4];
#pragma unroll
    for (int mi = 0; mi < 2; mi++)
#pragma unroll
        for (int r = 0; r < 4; r++) {
            size_t o = phBase + m0 + mi * 16 + quad * 4 + r;
            ci[mi][r] = alph * cosP[o];
            si[mi][r] = alph * sinP[o];
        }

    {   // stage kt=0 -> buf 0
        async_copy16(&Kg[base + (size_t)(0 * 64 + sj) * 64 + srot], &KsB[0][t * 8]);
        async_copy16(&Kg[base + (size_t)(0 * 64 + sj + 32) * 64 + srot], &KsB[0][2048 + t * 8]);
        async_copy16(&VTg[base + (size_t)sj * S_LEN + 0 * 64 + srot], &VtB[0][t * 8]);
        async_copy16(&VTg[base + (size_t)(sj + 32) * S_LEN + 0 * 64 + srot], &VtB[0][2048 + t * 8]);
        if (w == 0)      async_copy4(&cosP[phBase + 0 * 64 + lane], &csB[0][lane]);
        else if (w == 1) async_copy4(&sinP[phBase + 0 * 64 + lane], &csB[0][64 + lane]);
    }

    floatx4 oacc[2][4], lacc[2];
#pragma unroll
    for (int mi = 0; mi < 2; mi++) {
#pragma unroll
        for (int tt = 0; tt < 4; tt++) oacc[mi][tt] = (floatx4){0.f, 0.f, 0.f, 0.f};
        lacc[mi] = (floatx4){0.f, 0.f, 0.f, 0.f};
    }
    const short8 ones8 = {(short)0x3F80, (short)0x3F80, (short)0x3F80, (short)0x3F80,
                          (short)0x3F80, (short)0x3F80, (short)0x3F80, (short)0x3F80};

    // frag-read rotation (row&7 == l15&7 for all frag rows used)
    int rot = l15 & 7;
    int cb0 = 16 * ((quad + rot) & 7);        // bytes, k-chunk c=0
    int cb1 = 16 * ((quad + 4 + rot) & 7);    // bytes, k-chunk c=1

    for (int kt = 0; kt < 32; kt++) {
        int p = kt & 1;
        __syncthreads();   // copies for kt complete (vmcnt drain) + buf p^1 free
        if (kt < 31) {
            int kn = kt + 1, pn = p ^ 1;
            async_copy16(&Kg[base + (size_t)(kn * 64 + sj) * 64 + srot], &KsB[pn][t * 8]);
            async_copy16(&Kg[base + (size_t)(kn * 64 + sj + 32) * 64 + srot], &KsB[pn][2048 + t * 8]);
            async_copy16(&VTg[base + (size_t)sj * S_LEN + kn * 64 + srot], &VtB[pn][t * 8]);
            async_copy16(&VTg[base + (size_t)(sj + 32) * S_LEN + kn * 64 + srot], &VtB[pn][2048 + t * 8]);
            if (w == 0)      async_copy4(&cosP[phBase + kn * 64 + lane], &csB[pn][lane]);
            else if (w == 1) async_copy4(&sinP[phBase + kn * 64 + lane], &csB[pn][64 + lane]);
        }

        // QK^T: S(i,j) C-layout (i=quad*4+r, j=l15 per 16x16 subtile)
        floatx4 st[2][4];
#pragma unroll
        for (int jt = 0; jt < 4; jt++) {
            const char* kr = (const char*)&KsB[p][(jt * 16 + l15) * 64];
            short8 kf0 = *reinterpret_cast<const short8*>(kr + cb0);
            short8 kf1 = *reinterpret_cast<const short8*>(kr + cb1);
#pragma unroll
            for (int mi = 0; mi < 2; mi++) {
                floatx4 s = (floatx4){0.f, 0.f, 0.f, 0.f};
                s = __builtin_amdgcn_mfma_f32_16x16x32_bf16(qf[mi][0], kf0, s, 0, 0, 0);
                s = __builtin_amdgcn_mfma_f32_16x16x32_bf16(qf[mi][1], kf1, s, 0, 0, 0);
                st[mi][jt] = s;
            }
        }

        float cjv[4], sjv[4];
#pragma unroll
        for (int jt = 0; jt < 4; jt++) {
            cjv[jt] = csB[p][jt * 16 + l15];
            sjv[jt] = csB[p][64 + jt * 16 + l15];
        }

        // P = exp2(S + coherence) -> packed bf16 in Plb (pi column order)
        unsigned int* pl = reinterpret_cast<unsigned int*>(&Plb[w][0]);
#pragma unroll
        for (int mi = 0; mi < 2; mi++)
#pragma unroll
            for (int r = 0; r < 4; r++) {
                float cc = ci[mi][r], ss = si[mi][r];
                float p0 = __builtin_amdgcn_exp2f(st[mi][0][r] + cc * cjv[0] + ss * sjv[0]);
                float p1 = __builtin_amdgcn_exp2f(st[mi][1][r] + cc * cjv[1] + ss * sjv[1]);
                float p2 = __builtin_amdgcn_exp2f(st[mi][2][r] + cc * cjv[2] + ss * sjv[2]);
                float p3 = __builtin_amdgcn_exp2f(st[mi][3][r] + cc * cjv[3] + ss * sjv[3]);
                int row = mi * 16 + quad * 4 + r;
                pl[row * 36 + l15]      = pack2_bf16(p1, p0);
                pl[row * 36 + 16 + l15] = pack2_bf16(p3, p2);
            }

        // P A-frags (rows i, pi-ordered k)
        short8 pf[2][2];
#pragma unroll
        for (int mi = 0; mi < 2; mi++)
#pragma unroll
            for (int c = 0; c < 2; c++)
                pf[mi][c] = *reinterpret_cast<const short8*>(
                    &Plb[w][(mi * 16 + l15) * 72 + c * 32 + quad * 8]);

        // O += P @ V (B-frags from swizzled Vt); l += P @ ones
#pragma unroll
        for (int c = 0; c < 2; c++) {
            int cb = c ? cb1 : cb0;
#pragma unroll
            for (int tt = 0; tt < 4; tt++) {
                const char* vr = (const char*)&VtB[p][(tt * 16 + l15) * 64];
                short8 vf = *reinterpret_cast<const short8*>(vr + cb);
                oacc[0][tt] = __builtin_amdgcn_mfma_f32_16x16x32_bf16(pf[0][c], vf, oacc[0][tt], 0, 0, 0);
                oacc[1][tt] = __builtin_amdgcn_mfma_f32_16x16x32_bf16(pf[1][c], vf, oacc[1][tt], 0, 0, 0);
            }
            lacc[0] = __builtin_amdgcn_mfma_f32_16x16x32_bf16(pf[0][c], ones8, lacc[0], 0, 0, 0);
            lacc[1] = __builtin_amdgcn_mfma_f32_16x16x32_bf16(pf[1][c], ones8, lacc[1], 0, 0, 0);
        }
    }

    // epilogue: normalize rows by l (lacc all-cols-equal) and write ctx
    int b = bh >> 4, h = bh & 15;
#pragma unroll
    for (int mi = 0; mi < 2; mi++) {
        float inv[4];
#pragma unroll
        for (int r = 0; r < 4; r++) inv[r] = 1.0f / lacc[mi][r];
#pragma unroll
        for (int tt = 0; tt < 4; tt++)
#pragma unroll
            for (int r = 0; r < 4; r++) {
                int srow = m0 + mi * 16 + quad * 4 + r;
                ctx[((size_t)(b * S_LEN + srow)) * 1024 + h * 64 + tt * 16 + l15] =
                    f2bf(oacc[mi][tt][r] * inv[r]);
            }
    }
}

extern "C" void kernel_launch(void* const* d_in, const int* in_sizes, int n_in,
                              void* d_out, int out_size, void* d_ws, size_t ws_size,
                              hipStream_t stream) {
    const float* x     = (const float*)d_in[0];
    const float* Wq    = (const float*)d_in[1];
    const float* bq    = (const float*)d_in[2];
    const float* Wk    = (const float*)d_in[3];
    const float* bk    = (const float*)d_in[4];
    const float* Wv    = (const float*)d_in[5];
    const float* bv    = (const float*)d_in[6];
    const float* Wo    = (const float*)d_in[7];
    const float* bo    = (const float*)d_in[8];
    const float* Wp    = (const float*)d_in[9];
    const float* bp    = (const float*)d_in[10];
    const float* alpha = (const float*)d_in[11];
    float* out = (float*)d_out;

    const size_t MB = 1048576;
    char* ws = (char*)d_ws;
    unsigned short* WT   = (unsigned short*)(ws);             // 3072x1024 bf16
    unsigned short* WoT  = (unsigned short*)(ws + 6 * MB);    // 1024x1024 bf16
    unsigned short* xb   = (unsigned short*)(ws + 8 * MB);    // (B,S,D) bf16
    unsigned short* ctx  = (unsigned short*)(ws + 8 * MB);    // aliases xb
    unsigned short* Qw   = (unsigned short*)(ws + 16 * MB);   // (B,H,S,dk), pre-scaled
    unsigned short* Kw   = (unsigned short*)(ws + 24 * MB);   // (B,H,S,dk)
    unsigned short* VTg  = (unsigned short*)(ws + 32 * MB);   // (B,H,dk,S) -> pi-interleaved
    float* cosP          = (float*)(ws + 40 * MB);
    float* sinP          = (float*)(ws + 40 * MB + 262144);

    transpose4<<<dim3(1024), dim3(256), 0, stream>>>(
        Wq, Wk, Wv, Wo, WT, WT + 1048576, WT + 2097152, WoT);
    phase_cvt<<<dim3(4096), dim3(256), 0, stream>>>(
        x, Wp, bp, cosP, sinP, xb);
    gemm_bt<128><<<dim3(32, 24), dim3(256), 0, stream>>>(
        xb, WT, 3072, 1, bq, bk, bv, Qw, Kw, VTg, (float*)nullptr);
    vtrans<<<dim3(2048), dim3(256), 0, stream>>>((unsigned int*)VTg);
    attn_kernel<<<dim3(512), dim3(256), 0, stream>>>(
        Qw, Kw, VTg, cosP, sinP, alpha, ctx);
    gemm_bt<64><<<dim3(64, 8), dim3(256), 0, stream>>>(
        ctx, WoT, 1024, 0, bo, bo, bo,
        (unsigned short*)nullptr, (unsigned short*)nullptr,
        (unsigned short*)nullptr, out);
}

// Round 6
// 221.154 us; speedup vs baseline: 1.2823x; 1.0966x over previous
//
#include <hip/hip_runtime.h>
#include <math.h>

// OscillatoryAttention: B=2,S=2048,D=1024,H=16,dk=64. FP32 in/out, bf16 MFMA inside.
// R6: (1) attn 512-thr blocks (8 waves x 16 Q-rows) -> 16 waves/CU at same LDS;
//     (2) V pi-interleave folded into QKV-gemm epilogue (vtrans kernel dropped);
//     (3) transpose+phase fused into one prep kernel.

#define S_LEN 2048
#define NHEADS 16

typedef __attribute__((ext_vector_type(8))) short short8;
typedef __attribute__((ext_vector_type(4))) float floatx4;
typedef __attribute__((ext_vector_type(4))) unsigned int uintx4;

__device__ inline unsigned short f2bf(float f) {
    union { float f; unsigned int i; } v; v.f = f;
    unsigned int u = v.i;
    return (unsigned short)((u + 0x7fffu + ((u >> 16) & 1u)) >> 16);
}
// pack two f32 -> packed bf16 u32 (truncation), low short = lo
__device__ inline unsigned int pack2_bf16(float hi, float lo) {
    union { float f; unsigned int u; } a, b; a.f = hi; b.f = lo;
    return __builtin_amdgcn_perm(a.u, b.u, 0x07060302u);
}
__device__ inline void async_copy16(const unsigned short* src, unsigned short* dst_lds) {
    __builtin_amdgcn_global_load_lds(
        (const __attribute__((address_space(1))) unsigned int*)(src),
        (__attribute__((address_space(3))) unsigned int*)(dst_lds), 16, 0, 0);
}
__device__ inline void async_copy4(const float* src, float* dst_lds) {
    __builtin_amdgcn_global_load_lds(
        (const __attribute__((address_space(1))) unsigned int*)(src),
        (__attribute__((address_space(3))) unsigned int*)(dst_lds), 4, 0, 0);
}

// ---------------- prep: phase+cvt (blocks 0..4095) | weight transpose (4096..5119)
__global__ __launch_bounds__(256) void prep_kernel(
    const float* __restrict__ x, const float* __restrict__ Wp,
    const float* __restrict__ bp,
    const float* __restrict__ w0, const float* __restrict__ w1,
    const float* __restrict__ w2, const float* __restrict__ w3,
    unsigned short* __restrict__ d0, unsigned short* __restrict__ d1,
    unsigned short* __restrict__ d2, unsigned short* __restrict__ d3,
    float* __restrict__ cosP, float* __restrict__ sinP,
    unsigned short* __restrict__ xb) {
    __shared__ __align__(16) unsigned short shmem[64 * 72];   // 9216 B union
    int t = threadIdx.x;
    if (blockIdx.x < 4096) {
        float* red = reinterpret_cast<float*>(shmem);
        int bid = blockIdx.x;
        int b = bid >> 11, s = bid & 2047;
        int h = t & 15, c = t >> 4;
        const float* xr = x + (size_t)bid * 1024;
        {
            float4 xv = *reinterpret_cast<const float4*>(&xr[t * 4]);
            uint2 o;
            o.x = (unsigned int)f2bf(xv.x) | ((unsigned int)f2bf(xv.y) << 16);
            o.y = (unsigned int)f2bf(xv.z) | ((unsigned int)f2bf(xv.w) << 16);
            *reinterpret_cast<uint2*>(&xb[(size_t)bid * 1024 + t * 4]) = o;
        }
        float acc = 0.f;
#pragma unroll 8
        for (int kk = 0; kk < 64; kk++) {
            int k = c * 64 + kk;
            acc += xr[k] * Wp[k * 16 + h];
        }
        red[t] = acc;
        __syncthreads();
        if (t < 16) {
            float sum = 0.f;
#pragma unroll
            for (int c2 = 0; c2 < 16; c2++) sum += red[c2 * 16 + t];
            sum += bp[t];
            float sv, cv;
            __sincosf(sum, &sv, &cv);
            size_t o = ((size_t)b * NHEADS + t) * S_LEN + s;
            cosP[o] = cv; sinP[o] = sv;
        }
    } else {
        unsigned short (*tile)[72] = reinterpret_cast<unsigned short (*)[72]>(shmem);
        int bid = blockIdx.x - 4096;
        int mat = bid >> 8;
        int tl  = bid & 255;
        int tr = tl >> 4, tc = tl & 15;
        const float* src    = (mat == 0) ? w0 : (mat == 1) ? w1 : (mat == 2) ? w2 : w3;
        unsigned short* dst = (mat == 0) ? d0 : (mat == 1) ? d1 : (mat == 2) ? d2 : d3;
        int col = t & 63, rbase = (t >> 6) * 16;
#pragma unroll
        for (int i = 0; i < 16; i++) {
            int row = rbase + i;
            tile[row][col] = f2bf(src[(size_t)(tr * 64 + row) * 1024 + tc * 64 + col]);
        }
        __syncthreads();
#pragma unroll
        for (int i = 0; i < 16; i++) {
            int row = rbase + i;
            dst[(size_t)(tc * 64 + row) * 1024 + tr * 64 + col] = tile[col][row];
        }
    }
}

// ---------------- GEMM (m97 recipe) ---------------------------------------------
// mode 0: row-major fp32 out (+bias) -> of
// mode 1: N=3072 QKV: Q scaled 0.125*log2e -> (B,H,S,dk); K -> (B,H,S,dk);
//         V -> (B,H,dk,S) transposed AND pi-interleaved within 64-token chunks:
//         token j=32a+16c+b lands at short u=32a+2b+c.
template <int MT>
__global__ __launch_bounds__(256) void gemm_bt(
    const unsigned short* __restrict__ A, const unsigned short* __restrict__ BT,
    int N, int mode,
    const float* __restrict__ b0, const float* __restrict__ b1,
    const float* __restrict__ b2,
    unsigned short* __restrict__ o0, unsigned short* __restrict__ o1,
    unsigned short* __restrict__ o2, float* __restrict__ of) {
    __shared__ __align__(16) unsigned short As[MT * 32];
    __shared__ __align__(16) unsigned short Bs[128 * 32];
    const int K = 1024;
    const int MI = MT / 32;
    int t = threadIdx.x;
    int mBase = blockIdx.x * MT;
    int nBase = blockIdx.y * 128;
    int w = t >> 6, lane = t & 63, l15 = lane & 15, quad = lane >> 4;
    int wm = (w & 1) * (MT / 2), wn = (w >> 1) * 64;
    floatx4 acc[MI][4];
#pragma unroll
    for (int i = 0; i < MI; i++)
#pragma unroll
        for (int j = 0; j < 4; j++) acc[i][j] = (floatx4){0.f, 0.f, 0.f, 0.f};

    int arow = t >> 2, aseg = (t & 3) * 8;
    for (int k0 = 0; k0 < K; k0 += 32) {
        __syncthreads();
#pragma unroll
        for (int i = 0; i < MT / 64; i++)
            async_copy16(&A[(size_t)(mBase + i * 64 + arow) * K + k0 + aseg],
                         &As[(i * 64 + arow) * 32 + aseg]);
#pragma unroll
        for (int i = 0; i < 2; i++)
            async_copy16(&BT[(size_t)(nBase + i * 64 + arow) * K + k0 + aseg],
                         &Bs[(i * 64 + arow) * 32 + aseg]);
        __syncthreads();
        short8 af[MI], bfr[4];
#pragma unroll
        for (int mi = 0; mi < MI; mi++)
            af[mi] = *reinterpret_cast<const short8*>(&As[(wm + mi * 16 + l15) * 32 + quad * 8]);
#pragma unroll
        for (int ni = 0; ni < 4; ni++)
            bfr[ni] = *reinterpret_cast<const short8*>(&Bs[(wn + ni * 16 + l15) * 32 + quad * 8]);
#pragma unroll
        for (int mi = 0; mi < MI; mi++)
#pragma unroll
            for (int ni = 0; ni < 4; ni++)
                acc[mi][ni] = __builtin_amdgcn_mfma_f32_16x16x32_bf16(af[mi], bfr[ni], acc[mi][ni], 0, 0, 0);
    }

#pragma unroll
    for (int mi = 0; mi < MI; mi++) {
        int rowB = mBase + wm + mi * 16 + quad * 4;
#pragma unroll
        for (int ni = 0; ni < 4; ni++) {
            int col = nBase + wn + ni * 16 + l15;
            if (mode == 0) {
                float bias = b0[col];
#pragma unroll
                for (int r = 0; r < 4; r++) {
                    of[(size_t)(rowB + r) * N + col] = acc[mi][ni][r] + bias;
                }
            } else {
                int mat = col >> 10, nn = col & 1023;
                int h = nn >> 6, d = nn & 63;
                int b = rowB >> 11, sidx = rowB & 2047;
                if (mat == 2) {
                    float bv = b2[nn];
                    int jj = sidx & 63;                 // multiple of 4
                    int a2 = jj >> 5, c2 = (jj >> 4) & 1, bb = jj & 15;
                    size_t rowOff = ((size_t)((b * NHEADS + h) * 64 + d)) * S_LEN +
                                    (sidx & ~63) + a2 * 32 + c2;
#pragma unroll
                    for (int r = 0; r < 4; r++)
                        o2[rowOff + 2 * (bb + r)] = f2bf(acc[mi][ni][r] + bv);
                } else {
                    const float* bias  = (mat == 0) ? b0 : b1;
                    unsigned short* op = (mat == 0) ? o0 : o1;
                    float bv = bias[nn];
                    float scl = (mat == 0) ? 0.18033688f : 1.0f;  // dk^-0.5 * log2e
#pragma unroll
                    for (int r = 0; r < 4; r++) {
                        float cv = (acc[mi][ni][r] + bv) * scl;
                        op[(((size_t)b * NHEADS + h) * S_LEN + (sidx + r)) * 64 + d] = f2bf(cv);
                    }
                }
            }
        }
    }
}

// ---------------- flash attention, oscillatory coherence ------------------------
// grid = B*H*(S/128) = 512 blocks, 512 thr (8 waves x 16 Q-rows).
// Double-buffered async staging (1 copy/thread/tile), swizzled LDS, 1 barrier/iter.
__global__ __launch_bounds__(512) void attn_kernel(
    const unsigned short* __restrict__ Qg, const unsigned short* __restrict__ Kg,
    const unsigned short* __restrict__ VTg,
    const float* __restrict__ cosP, const float* __restrict__ sinP,
    const float* __restrict__ alpha, unsigned short* __restrict__ ctx) {
    __shared__ __align__(16) unsigned short KsB[2][64 * 64];
    __shared__ __align__(16) unsigned short VtB[2][64 * 64];
    __shared__ __align__(16) float csB[2][128];          // cos 0..63, sin 64..127
    __shared__ __align__(16) unsigned short Plb[8][16 * 72];

    int bid = blockIdx.x;
    int bh = bid >> 4, qt = bid & 15;
    int t = threadIdx.x, w = t >> 6, lane = t & 63, l15 = lane & 15, quad = lane >> 4;
    int m0 = qt * 128 + w * 16;
    size_t base = (size_t)bh * (S_LEN * 64);
    size_t phBase = (size_t)bh * S_LEN;
    const float L2E = 1.44269504f;

    // staging geometry: thread t owns LDS bytes [16t,16t+16) of each 8 KB tile
    int sj = t >> 3, sg = t & 7;
    int srot = ((sg - (sj & 7)) & 7) * 8;   // shorts: un-rotated global column

    // Q frags (A-layout); Q pre-scaled by 0.125*L2E
    short8 qf[2];
#pragma unroll
    for (int c = 0; c < 2; c++)
        qf[c] = *reinterpret_cast<const short8*>(
            &Qg[base + (size_t)(m0 + l15) * 64 + c * 32 + quad * 8]);

    float alph = alpha[bh & 15] * L2E;
    float ci[4], si[4];
#pragma unroll
    for (int r = 0; r < 4; r++) {
        size_t o = phBase + m0 + quad * 4 + r;
        ci[r] = alph * cosP[o];
        si[r] = alph * sinP[o];
    }

    {   // stage kt=0 -> buf 0
        async_copy16(&Kg[base + (size_t)sj * 64 + srot], &KsB[0][t * 8]);
        async_copy16(&VTg[base + (size_t)sj * S_LEN + srot], &VtB[0][t * 8]);
        if (w == 2)      async_copy4(&cosP[phBase + lane], &csB[0][lane]);
        else if (w == 3) async_copy4(&sinP[phBase + lane], &csB[0][64 + lane]);
    }

    floatx4 oacc[4], lacc;
#pragma unroll
    for (int tt = 0; tt < 4; tt++) oacc[tt] = (floatx4){0.f, 0.f, 0.f, 0.f};
    lacc = (floatx4){0.f, 0.f, 0.f, 0.f};
    const short8 ones8 = {(short)0x3F80, (short)0x3F80, (short)0x3F80, (short)0x3F80,
                          (short)0x3F80, (short)0x3F80, (short)0x3F80, (short)0x3F80};

    // frag-read rotation
    int rot = l15 & 7;
    int cb0 = 16 * ((quad + rot) & 7);        // bytes, k-chunk c=0
    int cb1 = 16 * ((quad + 4 + rot) & 7);    // bytes, k-chunk c=1

    for (int kt = 0; kt < 32; kt++) {
        int p = kt & 1;
        __syncthreads();   // drains async copies for kt; buf p^1 free
        if (kt < 31) {
            int kn = kt + 1, pn = p ^ 1;
            async_copy16(&Kg[base + (size_t)(kn * 64 + sj) * 64 + srot], &KsB[pn][t * 8]);
            async_copy16(&VTg[base + (size_t)sj * S_LEN + kn * 64 + srot], &VtB[pn][t * 8]);
            if (w == 2)      async_copy4(&cosP[phBase + kn * 64 + lane], &csB[pn][lane]);
            else if (w == 3) async_copy4(&sinP[phBase + kn * 64 + lane], &csB[pn][64 + lane]);
        }

        // QK^T: S(i,j) C-layout (i=quad*4+r, j=l15 per 16-subtile)
        floatx4 st[4];
#pragma unroll
        for (int jt = 0; jt < 4; jt++) {
            const char* kr = (const char*)&KsB[p][(jt * 16 + l15) * 64];
            short8 kf0 = *reinterpret_cast<const short8*>(kr + cb0);
            short8 kf1 = *reinterpret_cast<const short8*>(kr + cb1);
            floatx4 s = (floatx4){0.f, 0.f, 0.f, 0.f};
            s = __builtin_amdgcn_mfma_f32_16x16x32_bf16(qf[0], kf0, s, 0, 0, 0);
            s = __builtin_amdgcn_mfma_f32_16x16x32_bf16(qf[1], kf1, s, 0, 0, 0);
            st[jt] = s;
        }

        float cjv[4], sjv[4];
#pragma unroll
        for (int jt = 0; jt < 4; jt++) {
            cjv[jt] = csB[p][jt * 16 + l15];
            sjv[jt] = csB[p][64 + jt * 16 + l15];
        }

        // P = exp2(S + coherence) -> packed bf16 in Plb[w] (pi column order)
        unsigned int* pl = reinterpret_cast<unsigned int*>(&Plb[w][0]);
#pragma unroll
        for (int r = 0; r < 4; r++) {
            float cc = ci[r], ss = si[r];
            float p0 = __builtin_amdgcn_exp2f(st[0][r] + cc * cjv[0] + ss * sjv[0]);
            float p1 = __builtin_amdgcn_exp2f(st[1][r] + cc * cjv[1] + ss * sjv[1]);
            float p2 = __builtin_amdgcn_exp2f(st[2][r] + cc * cjv[2] + ss * sjv[2]);
            float p3 = __builtin_amdgcn_exp2f(st[3][r] + cc * cjv[3] + ss * sjv[3]);
            int row = quad * 4 + r;
            pl[row * 36 + l15]      = pack2_bf16(p1, p0);
            pl[row * 36 + 16 + l15] = pack2_bf16(p3, p2);
        }

        // P A-frags (rows i, pi-ordered k)
        short8 pf[2];
#pragma unroll
        for (int c = 0; c < 2; c++)
            pf[c] = *reinterpret_cast<const short8*>(
                &Plb[w][l15 * 72 + c * 32 + quad * 8]);

        // O += P @ V; l += P @ ones
#pragma unroll
        for (int c = 0; c < 2; c++) {
            int cb = c ? cb1 : cb0;
#pragma unroll
            for (int tt = 0; tt < 4; tt++) {
                const char* vr = (const char*)&VtB[p][(tt * 16 + l15) * 64];
                short8 vf = *reinterpret_cast<const short8*>(vr + cb);
                oacc[tt] = __builtin_amdgcn_mfma_f32_16x16x32_bf16(pf[c], vf, oacc[tt], 0, 0, 0);
            }
            lacc = __builtin_amdgcn_mfma_f32_16x16x32_bf16(pf[c], ones8, lacc, 0, 0, 0);
        }
    }

    // epilogue: normalize rows by l and write ctx[b][s][h*64+d]
    int b = bh >> 4, h = bh & 15;
    float inv[4];
#pragma unroll
    for (int r = 0; r < 4; r++) inv[r] = 1.0f / lacc[r];
#pragma unroll
    for (int tt = 0; tt < 4; tt++)
#pragma unroll
        for (int r = 0; r < 4; r++) {
            int srow = m0 + quad * 4 + r;
            ctx[((size_t)(b * S_LEN + srow)) * 1024 + h * 64 + tt * 16 + l15] =
                f2bf(oacc[tt][r] * inv[r]);
        }
}

extern "C" void kernel_launch(void* const* d_in, const int* in_sizes, int n_in,
                              void* d_out, int out_size, void* d_ws, size_t ws_size,
                              hipStream_t stream) {
    const float* x     = (const float*)d_in[0];
    const float* Wq    = (const float*)d_in[1];
    const float* bq    = (const float*)d_in[2];
    const float* Wk    = (const float*)d_in[3];
    const float* bk    = (const float*)d_in[4];
    const float* Wv    = (const float*)d_in[5];
    const float* bv    = (const float*)d_in[6];
    const float* Wo    = (const float*)d_in[7];
    const float* bo    = (const float*)d_in[8];
    const float* Wp    = (const float*)d_in[9];
    const float* bp    = (const float*)d_in[10];
    const float* alpha = (const float*)d_in[11];
    float* out = (float*)d_out;

    const size_t MB = 1048576;
    char* ws = (char*)d_ws;
    unsigned short* WT   = (unsigned short*)(ws);             // 3072x1024 bf16
    unsigned short* WoT  = (unsigned short*)(ws + 6 * MB);    // 1024x1024 bf16
    unsigned short* xb   = (unsigned short*)(ws + 8 * MB);    // (B,S,D) bf16
    unsigned short* ctx  = (unsigned short*)(ws + 8 * MB);    // aliases xb
    unsigned short* Qw   = (unsigned short*)(ws + 16 * MB);   // (B,H,S,dk), pre-scaled
    unsigned short* Kw   = (unsigned short*)(ws + 24 * MB);   // (B,H,S,dk)
    unsigned short* VTg  = (unsigned short*)(ws + 32 * MB);   // (B,H,dk,S) pi-interleaved
    float* cosP          = (float*)(ws + 40 * MB);
    float* sinP          = (float*)(ws + 40 * MB + 262144);

    prep_kernel<<<dim3(5120), dim3(256), 0, stream>>>(
        x, Wp, bp, Wq, Wk, Wv, Wo,
        WT, WT + 1048576, WT + 2097152, WoT, cosP, sinP, xb);
    gemm_bt<128><<<dim3(32, 24), dim3(256), 0, stream>>>(
        xb, WT, 3072, 1, bq, bk, bv, Qw, Kw, VTg, (float*)nullptr);
    attn_kernel<<<dim3(512), dim3(512), 0, stream>>>(
        Qw, Kw, VTg, cosP, sinP, alpha, ctx);
    gemm_bt<64><<<dim3(64, 8), dim3(256), 0, stream>>>(
        ctx, WoT, 1024, 0, bo, bo, bo,
        (unsigned short*)nullptr, (unsigned short*)nullptr,
        (unsigned short*)nullptr, out);
}